// Round 3
// baseline (233.583 us; speedup 1.0000x reference)
//
#include <hip/hip_runtime.h>
#include <hip/hip_bf16.h>

// ---------------------------------------------------------------------------
// Modnet2: out[i] = sum_j y_j * ( tanh( tanh(A_i + B_j) @ W2 + b2 ) @ W3 + b3 )
//   A[i][h] = s*(input[i,0:2] @ W1[0:2,h])          (s = 2*log2(e) folded in)
//   B[j][h] = s*(quad_x[j,0:2] @ W1[2:4,h] + b1[h])
//   W2T/b2 pre-scaled by s, so tanh(x) = 1 - 2*rcp(1 + exp2(x_scaled)).
//
// R3: occupancy fix. 2-wave blocks (32i x 128n x 16j), grid 64x32 = 2048
// blocks = 8 blocks/CU = 16 waves/CU (50%). Wave p owns k-chunks {2p,2p+1}
// and n-half p; layer-1 bf16 fragments computed once and exchanged through a
// single-buffered 8KB LDS area (2 barriers/j). W3 folded into epilogue.
// ---------------------------------------------------------------------------

using short8 = __attribute__((ext_vector_type(8))) short;   // 8 bf16 = 4 VGPR
using f32x4  = __attribute__((ext_vector_type(4))) float;   // MFMA C/D frag

#define N_IN   2048
#define M_Q    512
#define H_DIM  128
#define JC     32
#define JCHUNK 16      // M_Q / JC

// ws byte offsets
#define WS_A_OFF     0x000000u   // 2048*128 f32 = 1 MiB   (pre-scaled)
#define WS_B_OFF     0x100000u   //  512*128 f32 = 256 KiB (pre-scaled)
#define WS_Y_OFF     0x140000u   //  512 f32
#define WS_SUMY_OFF  0x140800u   //  1 f32
#define WS_W2T_OFF   0x141000u   //  128*128 bf16 = 32 KiB (pre-scaled)
#define WS_SP_OFF    0x150000u   //  64 * 2048 f32 = 512 KiB (n-reduced partials)

#define PI_F   3.14159265358979323846f
#define TSCALE 2.885390081777927f   // 2*log2(e)

// x pre-scaled by TSCALE: tanh = 1 - 2/(1+e^{2x}) = 1 - 2*rcp(1+exp2(xs))
__device__ __forceinline__ float tanh_pre(float xs) {
    float t = __builtin_amdgcn_exp2f(xs);
    float r = __builtin_amdgcn_rcpf(1.0f + t);
    return __builtin_fmaf(-2.0f, r, 1.0f);
}

__device__ __forceinline__ unsigned short bf16b(float f) {
    __hip_bfloat16 h = __float2bfloat16(f);   // RNE
    unsigned short u;
    __builtin_memcpy(&u, &h, 2);
    return u;
}

// one MFMA A-fragment: 8 bf16 = tanh(a + b), inputs pre-scaled
__device__ __forceinline__ void conv8(const float4& a0, const float4& a1,
                                      const float4& b0, const float4& b1,
                                      short8& dst) {
    dst[0] = (short)bf16b(tanh_pre(a0.x + b0.x));
    dst[1] = (short)bf16b(tanh_pre(a0.y + b0.y));
    dst[2] = (short)bf16b(tanh_pre(a0.z + b0.z));
    dst[3] = (short)bf16b(tanh_pre(a0.w + b0.w));
    dst[4] = (short)bf16b(tanh_pre(a1.x + b1.x));
    dst[5] = (short)bf16b(tanh_pre(a1.y + b1.y));
    dst[6] = (short)bf16b(tanh_pre(a1.z + b1.z));
    dst[7] = (short)bf16b(tanh_pre(a1.w + b1.w));
}

// ---------------------------------------------------------------------------
// k_pre: A, B (scaled), y, sumy, W2T (scaled bf16)
// ---------------------------------------------------------------------------
__global__ void k_pre(const float* __restrict__ input, const float* __restrict__ qx,
                      const float* __restrict__ eq, const float* __restrict__ W1,
                      const float* __restrict__ b1, const float* __restrict__ W2,
                      float* __restrict__ ws) {
    int b = blockIdx.x, t = threadIdx.x;
    float* A = ws + (WS_A_OFF >> 2);
    float* B = ws + (WS_B_OFF >> 2);
    float* Y = ws + (WS_Y_OFF >> 2);
    unsigned short* W2T = (unsigned short*)((char*)ws + WS_W2T_OFF);

    if (b < 1024) {                       // A[i][h] (scaled)
        int idx = b * 256 + t;
        int i = idx >> 7, h = idx & 127;
        A[idx] = TSCALE * (input[2 * i] * W1[h] + input[2 * i + 1] * W1[128 + h]);
    } else if (b < 1280) {                // B[j][h] (scaled, + b1)
        int idx = (b - 1024) * 256 + t;
        int j = idx >> 7, h = idx & 127;
        B[idx] = TSCALE * (qx[2 * j] * W1[256 + h] + qx[2 * j + 1] * W1[384 + h] + b1[h]);
    } else if (b < 1344) {                // W2T[n][k] = bf16(s*W2[k][n])
        int idx = (b - 1280) * 256 + t;
        int n = idx >> 7, k = idx & 127;
        W2T[idx] = bf16b(TSCALE * W2[k * 128 + n]);
    } else {                              // y[j], sumy
        float e = eq[0];
        float s = 0.f;
        for (int rep = 0; rep < 2; ++rep) {
            int j = t + rep * 256;
            float yv = sinf(PI_F * e * qx[2 * j]) * sinf(PI_F * e * qx[2 * j + 1]);
            Y[j] = yv;
            s += yv;
        }
        __shared__ float red[4];
        for (int off = 32; off; off >>= 1) s += __shfl_down(s, off);
        if ((t & 63) == 0) red[t >> 6] = s;
        __syncthreads();
        if (t == 0) ws[WS_SUMY_OFF >> 2] = red[0] + red[1] + red[2] + red[3];
    }
}

// ---------------------------------------------------------------------------
// k_main. grid (64 i-blocks, 32 j-chunks) x 128 threads (2 waves).
// wave p: n-cols [64p, 64p+64), owns k-chunks {2p, 2p+1} for all 32 i-rows.
// mfma_f32_16x16x32_bf16 layout (verified R1/R2):
//   A: lane l -> row l&15, k=(l>>4)*8+e ; B: lane l -> col l&15, k=(l>>4)*8+e
//   D: lane l reg r -> row (l>>4)*4+r, col l&15
// ---------------------------------------------------------------------------
__global__ __launch_bounds__(128, 4)
void k_main(const float* __restrict__ A, const float* __restrict__ B,
            const float* __restrict__ Y, const unsigned short* __restrict__ W2T,
            const float* __restrict__ b2, const float* __restrict__ W3,
            float* __restrict__ Sp) {
    __shared__ float Bs[JCHUNK * 128];                  // 8 KB
    __shared__ float ys[JCHUNK];
    __shared__ unsigned short xbuf[4 * 2 * 512];        // kc x rb x 1KB = 8 KB

    int t = threadIdx.x;
    int p = t >> 6, lane = t & 63;
    int l16 = lane & 15, lg = lane >> 4;
    int ibW = blockIdx.x * 32;
    int jbase = blockIdx.y * JCHUNK;
    int myk0 = 2 * p;                 // own k-chunk base
    int otk0 = 2 * (1 - p);           // partner's k-chunk base

    // stage B chunk + y into LDS (coalesced)
    for (int off4 = t; off4 < (JCHUNK * 128) >> 2; off4 += 128)
        *(float4*)&Bs[off4 * 4] = *(const float4*)&B[jbase * 128 + off4 * 4];
    if (t < JCHUNK) ys[t] = Y[jbase + t];

    // A-addends for OWN k-chunks only: aa[rb][kco][2]
    float4 aa[2][2][2];
#pragma unroll
    for (int rb = 0; rb < 2; ++rb)
#pragma unroll
        for (int kco = 0; kco < 2; ++kco) {
            const float* pa = &A[(ibW + rb * 16 + l16) * 128 + (myk0 + kco) * 32 + lg * 8];
            aa[rb][kco][0] = *(const float4*)pa;
            aa[rb][kco][1] = *(const float4*)(pa + 4);
        }

    // W2 fragments for this wave's 64 n, all 128 k (own-k and partner-k sets)
    short8 wfo[4][2], wfx[4][2];
#pragma unroll
    for (int nb = 0; nb < 4; ++nb)
#pragma unroll
        for (int kco = 0; kco < 2; ++kco) {
            int nrow = (p * 64 + nb * 16 + l16) * 128 + lg * 8;
            wfo[nb][kco] = *(const short8*)&W2T[nrow + (myk0 + kco) * 32];
            wfx[nb][kco] = *(const short8*)&W2T[nrow + (otk0 + kco) * 32];
        }

    float b2v[4], w3v[4];
#pragma unroll
    for (int nb = 0; nb < 4; ++nb) {
        b2v[nb] = TSCALE * b2[p * 64 + nb * 16 + l16];
        w3v[nb] = W3[p * 64 + nb * 16 + l16];
    }

    unsigned short* xw = xbuf + myk0 * 2 * 512 + lane * 8;
    unsigned short* xr = xbuf + otk0 * 2 * 512 + lane * 8;

    __syncthreads();

    f32x4 acc[2][4] = {};

#pragma unroll 1
    for (int jj = 0; jj < JCHUNK; ++jj) {
        // convert own k-chunks: av[kco][rb]
        short8 av[2][2];
#pragma unroll
        for (int kco = 0; kco < 2; ++kco) {
            const float* bp = &Bs[jj * 128 + (myk0 + kco) * 32 + lg * 8];
            float4 bj0 = *(const float4*)bp;
            float4 bj1 = *(const float4*)(bp + 4);
#pragma unroll
            for (int rb = 0; rb < 2; ++rb)
                conv8(aa[rb][kco][0], aa[rb][kco][1], bj0, bj1, av[kco][rb]);
        }

        __syncthreads();   // partner finished reading xbuf (prev iter)

#pragma unroll
        for (int kco = 0; kco < 2; ++kco)
#pragma unroll
            for (int rb = 0; rb < 2; ++rb)
                *(short8*)(xw + (kco * 2 + rb) * 512) = av[kco][rb];

        __syncthreads();   // writes visible

        short8 avx[2][2];
#pragma unroll
        for (int kco = 0; kco < 2; ++kco)
#pragma unroll
            for (int rb = 0; rb < 2; ++rb)
                avx[kco][rb] = *(const short8*)(xr + (kco * 2 + rb) * 512);

        // o = b2 + H1 @ W2  (own k from regs, partner k from LDS)
        f32x4 o[2][4];
#pragma unroll
        for (int rb = 0; rb < 2; ++rb)
#pragma unroll
            for (int nb = 0; nb < 4; ++nb) {
                o[rb][nb][0] = b2v[nb]; o[rb][nb][1] = b2v[nb];
                o[rb][nb][2] = b2v[nb]; o[rb][nb][3] = b2v[nb];
            }
#pragma unroll
        for (int kco = 0; kco < 2; ++kco)
#pragma unroll
            for (int rb = 0; rb < 2; ++rb)
#pragma unroll
                for (int nb = 0; nb < 4; ++nb)
                    o[rb][nb] = __builtin_amdgcn_mfma_f32_16x16x32_bf16(
                        av[kco][rb], wfo[nb][kco], o[rb][nb], 0, 0, 0);
#pragma unroll
        for (int kco = 0; kco < 2; ++kco)
#pragma unroll
            for (int rb = 0; rb < 2; ++rb)
#pragma unroll
                for (int nb = 0; nb < 4; ++nb)
                    o[rb][nb] = __builtin_amdgcn_mfma_f32_16x16x32_bf16(
                        avx[kco][rb], wfx[nb][kco], o[rb][nb], 0, 0, 0);

        // layer-2 tanh (o pre-scaled) + y-weighted accumulate
        float yj = ys[jj];
#pragma unroll
        for (int rb = 0; rb < 2; ++rb)
#pragma unroll
            for (int nb = 0; nb < 4; ++nb)
#pragma unroll
                for (int r = 0; r < 4; ++r)
                    acc[rb][nb][r] = __builtin_fmaf(yj, tanh_pre(o[rb][nb][r]),
                                                    acc[rb][nb][r]);
    }

    // epilogue: fold W3 over this wave's 64 n, reduce across l16, write partial
    float s[2][4];
#pragma unroll
    for (int rb = 0; rb < 2; ++rb)
#pragma unroll
        for (int r = 0; r < 4; ++r) {
            float v = 0.f;
#pragma unroll
            for (int nb = 0; nb < 4; ++nb)
                v = __builtin_fmaf(acc[rb][nb][r], w3v[nb], v);
            s[rb][r] = v;
        }
#pragma unroll
    for (int m = 1; m < 16; m <<= 1)
#pragma unroll
        for (int rb = 0; rb < 2; ++rb)
#pragma unroll
            for (int r = 0; r < 4; ++r)
                s[rb][r] += __shfl_xor(s[rb][r], m);

    if (l16 == 0) {
        float* dst = Sp + (blockIdx.y * 2 + p) * N_IN;
#pragma unroll
        for (int rb = 0; rb < 2; ++rb)
#pragma unroll
            for (int r = 0; r < 4; ++r)
                dst[ibW + rb * 16 + lg * 4 + r] = s[rb][r];
    }
}

// ---------------------------------------------------------------------------
// k_fin: out[i] = sum_{s<64} Sp[s][i] + b3*sumy.  grid 8 x 256.
// ---------------------------------------------------------------------------
__global__ void k_fin(const float* __restrict__ Sp, const float* __restrict__ b3,
                      const float* __restrict__ ws, float* __restrict__ out) {
    int i = blockIdx.x * 256 + threadIdx.x;
    float acc = b3[0] * ws[WS_SUMY_OFF >> 2];
#pragma unroll
    for (int s = 0; s < 2 * JC; ++s) acc += Sp[s * N_IN + i];
    out[i] = acc;
}

// ---------------------------------------------------------------------------
extern "C" void kernel_launch(void* const* d_in, const int* in_sizes, int n_in,
                              void* d_out, int out_size, void* d_ws, size_t ws_size,
                              hipStream_t stream) {
    const float* input = (const float*)d_in[0];
    const float* qx    = (const float*)d_in[1];
    const float* eq    = (const float*)d_in[2];
    const float* W1    = (const float*)d_in[3];
    const float* b1    = (const float*)d_in[4];
    const float* W2    = (const float*)d_in[5];
    const float* b2    = (const float*)d_in[6];
    const float* W3    = (const float*)d_in[7];
    const float* b3    = (const float*)d_in[8];
    float* out = (float*)d_out;
    float* ws  = (float*)d_ws;

    const float* A = ws + (WS_A_OFF >> 2);
    const float* B = ws + (WS_B_OFF >> 2);
    const float* Y = ws + (WS_Y_OFF >> 2);
    const unsigned short* W2T = (const unsigned short*)((char*)d_ws + WS_W2T_OFF);
    float* Sp = (float*)((char*)d_ws + WS_SP_OFF);

    k_pre<<<1345, 256, 0, stream>>>(input, qx, eq, W1, b1, W2, ws);
    k_main<<<dim3(64, JC), 128, 0, stream>>>(A, B, Y, W2T, b2, W3, Sp);
    k_fin<<<8, 256, 0, stream>>>(Sp, b3, ws, out);
}

// Round 4
// 110.864 us; speedup vs baseline: 2.1069x; 2.1069x over previous
//
#include <hip/hip_runtime.h>
#include <hip/hip_bf16.h>

// ---------------------------------------------------------------------------
// Modnet2: out[i] = sum_j y_j * ( tanh( tanh(A_i + B_j) @ W2 + b2 ) @ W3 + b3 )
//   A[i][h] = s*(input[i,0:2] @ W1[0:2,h])          (s = 2*log2(e) folded in)
//   B[j][h] = s*(quad_x[j,0:2] @ W1[2:4,h] + b1[h])
//   W2T/b2 pre-scaled by s, so tanh(x) = 1 - 2*rcp(1 + exp2(x_scaled)).
//
// R4: same structure as R3 (2-wave blocks, 32i x 128n x 16j, grid 64x32 =
// 2048 blocks = 8 blocks/CU = 4 waves/SIMD) but __launch_bounds__(128, 2):
// R3's (128,4) capped VGPRs at 64 and spilled ~50 regs to scratch
// (FETCH_SIZE 1.7MB -> 664MB, 83 -> 234us). Cap 256 removes the spills;
// occupancy binds on grid/LDS at the intended 50%.
// ---------------------------------------------------------------------------

using short8 = __attribute__((ext_vector_type(8))) short;   // 8 bf16 = 4 VGPR
using f32x4  = __attribute__((ext_vector_type(4))) float;   // MFMA C/D frag

#define N_IN   2048
#define M_Q    512
#define H_DIM  128
#define JC     32
#define JCHUNK 16      // M_Q / JC

// ws byte offsets
#define WS_A_OFF     0x000000u   // 2048*128 f32 = 1 MiB   (pre-scaled)
#define WS_B_OFF     0x100000u   //  512*128 f32 = 256 KiB (pre-scaled)
#define WS_Y_OFF     0x140000u   //  512 f32
#define WS_SUMY_OFF  0x140800u   //  1 f32
#define WS_W2T_OFF   0x141000u   //  128*128 bf16 = 32 KiB (pre-scaled)
#define WS_SP_OFF    0x150000u   //  64 * 2048 f32 = 512 KiB (n-reduced partials)

#define PI_F   3.14159265358979323846f
#define TSCALE 2.885390081777927f   // 2*log2(e)

// x pre-scaled by TSCALE: tanh = 1 - 2/(1+e^{2x}) = 1 - 2*rcp(1+exp2(xs))
__device__ __forceinline__ float tanh_pre(float xs) {
    float t = __builtin_amdgcn_exp2f(xs);
    float r = __builtin_amdgcn_rcpf(1.0f + t);
    return __builtin_fmaf(-2.0f, r, 1.0f);
}

__device__ __forceinline__ unsigned short bf16b(float f) {
    __hip_bfloat16 h = __float2bfloat16(f);   // RNE
    unsigned short u;
    __builtin_memcpy(&u, &h, 2);
    return u;
}

// one MFMA A-fragment: 8 bf16 = tanh(a + b), inputs pre-scaled
__device__ __forceinline__ void conv8(const float4& a0, const float4& a1,
                                      const float4& b0, const float4& b1,
                                      short8& dst) {
    dst[0] = (short)bf16b(tanh_pre(a0.x + b0.x));
    dst[1] = (short)bf16b(tanh_pre(a0.y + b0.y));
    dst[2] = (short)bf16b(tanh_pre(a0.z + b0.z));
    dst[3] = (short)bf16b(tanh_pre(a0.w + b0.w));
    dst[4] = (short)bf16b(tanh_pre(a1.x + b1.x));
    dst[5] = (short)bf16b(tanh_pre(a1.y + b1.y));
    dst[6] = (short)bf16b(tanh_pre(a1.z + b1.z));
    dst[7] = (short)bf16b(tanh_pre(a1.w + b1.w));
}

// ---------------------------------------------------------------------------
// k_pre: A, B (scaled), y, sumy, W2T (scaled bf16)
// ---------------------------------------------------------------------------
__global__ void k_pre(const float* __restrict__ input, const float* __restrict__ qx,
                      const float* __restrict__ eq, const float* __restrict__ W1,
                      const float* __restrict__ b1, const float* __restrict__ W2,
                      float* __restrict__ ws) {
    int b = blockIdx.x, t = threadIdx.x;
    float* A = ws + (WS_A_OFF >> 2);
    float* B = ws + (WS_B_OFF >> 2);
    float* Y = ws + (WS_Y_OFF >> 2);
    unsigned short* W2T = (unsigned short*)((char*)ws + WS_W2T_OFF);

    if (b < 1024) {                       // A[i][h] (scaled)
        int idx = b * 256 + t;
        int i = idx >> 7, h = idx & 127;
        A[idx] = TSCALE * (input[2 * i] * W1[h] + input[2 * i + 1] * W1[128 + h]);
    } else if (b < 1280) {                // B[j][h] (scaled, + b1)
        int idx = (b - 1024) * 256 + t;
        int j = idx >> 7, h = idx & 127;
        B[idx] = TSCALE * (qx[2 * j] * W1[256 + h] + qx[2 * j + 1] * W1[384 + h] + b1[h]);
    } else if (b < 1344) {                // W2T[n][k] = bf16(s*W2[k][n])
        int idx = (b - 1280) * 256 + t;
        int n = idx >> 7, k = idx & 127;
        W2T[idx] = bf16b(TSCALE * W2[k * 128 + n]);
    } else {                              // y[j], sumy
        float e = eq[0];
        float s = 0.f;
        for (int rep = 0; rep < 2; ++rep) {
            int j = t + rep * 256;
            float yv = sinf(PI_F * e * qx[2 * j]) * sinf(PI_F * e * qx[2 * j + 1]);
            Y[j] = yv;
            s += yv;
        }
        __shared__ float red[4];
        for (int off = 32; off; off >>= 1) s += __shfl_down(s, off);
        if ((t & 63) == 0) red[t >> 6] = s;
        __syncthreads();
        if (t == 0) ws[WS_SUMY_OFF >> 2] = red[0] + red[1] + red[2] + red[3];
    }
}

// ---------------------------------------------------------------------------
// k_main. grid (64 i-blocks, 32 j-chunks) x 128 threads (2 waves).
// wave p: n-cols [64p, 64p+64), owns k-chunks {2p, 2p+1} for all 32 i-rows.
// mfma_f32_16x16x32_bf16 layout (verified R1/R2):
//   A: lane l -> row l&15, k=(l>>4)*8+e ; B: lane l -> col l&15, k=(l>>4)*8+e
//   D: lane l reg r -> row (l>>4)*4+r, col l&15
// ---------------------------------------------------------------------------
__global__ __launch_bounds__(128, 2)
void k_main(const float* __restrict__ A, const float* __restrict__ B,
            const float* __restrict__ Y, const unsigned short* __restrict__ W2T,
            const float* __restrict__ b2, const float* __restrict__ W3,
            float* __restrict__ Sp) {
    __shared__ float Bs[JCHUNK * 128];                  // 8 KB
    __shared__ float ys[JCHUNK];
    __shared__ unsigned short xbuf[4 * 2 * 512];        // kc x rb x 1KB = 8 KB

    int t = threadIdx.x;
    int p = t >> 6, lane = t & 63;
    int l16 = lane & 15, lg = lane >> 4;
    int ibW = blockIdx.x * 32;
    int jbase = blockIdx.y * JCHUNK;
    int myk0 = 2 * p;                 // own k-chunk base
    int otk0 = 2 * (1 - p);           // partner's k-chunk base

    // stage B chunk + y into LDS (coalesced)
    for (int off4 = t; off4 < (JCHUNK * 128) >> 2; off4 += 128)
        *(float4*)&Bs[off4 * 4] = *(const float4*)&B[jbase * 128 + off4 * 4];
    if (t < JCHUNK) ys[t] = Y[jbase + t];

    // A-addends for OWN k-chunks only: aa[rb][kco][2]
    float4 aa[2][2][2];
#pragma unroll
    for (int rb = 0; rb < 2; ++rb)
#pragma unroll
        for (int kco = 0; kco < 2; ++kco) {
            const float* pa = &A[(ibW + rb * 16 + l16) * 128 + (myk0 + kco) * 32 + lg * 8];
            aa[rb][kco][0] = *(const float4*)pa;
            aa[rb][kco][1] = *(const float4*)(pa + 4);
        }

    // W2 fragments for this wave's 64 n, all 128 k (own-k and partner-k sets)
    short8 wfo[4][2], wfx[4][2];
#pragma unroll
    for (int nb = 0; nb < 4; ++nb)
#pragma unroll
        for (int kco = 0; kco < 2; ++kco) {
            int nrow = (p * 64 + nb * 16 + l16) * 128 + lg * 8;
            wfo[nb][kco] = *(const short8*)&W2T[nrow + (myk0 + kco) * 32];
            wfx[nb][kco] = *(const short8*)&W2T[nrow + (otk0 + kco) * 32];
        }

    float b2v[4], w3v[4];
#pragma unroll
    for (int nb = 0; nb < 4; ++nb) {
        b2v[nb] = TSCALE * b2[p * 64 + nb * 16 + l16];
        w3v[nb] = W3[p * 64 + nb * 16 + l16];
    }

    unsigned short* xw = xbuf + myk0 * 2 * 512 + lane * 8;
    unsigned short* xr = xbuf + otk0 * 2 * 512 + lane * 8;

    __syncthreads();

    f32x4 acc[2][4] = {};

#pragma unroll 1
    for (int jj = 0; jj < JCHUNK; ++jj) {
        // convert own k-chunks: av[kco][rb]
        short8 av[2][2];
#pragma unroll
        for (int kco = 0; kco < 2; ++kco) {
            const float* bp = &Bs[jj * 128 + (myk0 + kco) * 32 + lg * 8];
            float4 bj0 = *(const float4*)bp;
            float4 bj1 = *(const float4*)(bp + 4);
#pragma unroll
            for (int rb = 0; rb < 2; ++rb)
                conv8(aa[rb][kco][0], aa[rb][kco][1], bj0, bj1, av[kco][rb]);
        }

        __syncthreads();   // partner finished reading xbuf (prev iter)

#pragma unroll
        for (int kco = 0; kco < 2; ++kco)
#pragma unroll
            for (int rb = 0; rb < 2; ++rb)
                *(short8*)(xw + (kco * 2 + rb) * 512) = av[kco][rb];

        __syncthreads();   // writes visible

        short8 avx[2][2];
#pragma unroll
        for (int kco = 0; kco < 2; ++kco)
#pragma unroll
            for (int rb = 0; rb < 2; ++rb)
                avx[kco][rb] = *(const short8*)(xr + (kco * 2 + rb) * 512);

        // o = b2 + H1 @ W2  (own k from regs, partner k from LDS)
        f32x4 o[2][4];
#pragma unroll
        for (int rb = 0; rb < 2; ++rb)
#pragma unroll
            for (int nb = 0; nb < 4; ++nb) {
                o[rb][nb][0] = b2v[nb]; o[rb][nb][1] = b2v[nb];
                o[rb][nb][2] = b2v[nb]; o[rb][nb][3] = b2v[nb];
            }
#pragma unroll
        for (int kco = 0; kco < 2; ++kco)
#pragma unroll
            for (int rb = 0; rb < 2; ++rb)
#pragma unroll
                for (int nb = 0; nb < 4; ++nb)
                    o[rb][nb] = __builtin_amdgcn_mfma_f32_16x16x32_bf16(
                        av[kco][rb], wfo[nb][kco], o[rb][nb], 0, 0, 0);
#pragma unroll
        for (int kco = 0; kco < 2; ++kco)
#pragma unroll
            for (int rb = 0; rb < 2; ++rb)
#pragma unroll
                for (int nb = 0; nb < 4; ++nb)
                    o[rb][nb] = __builtin_amdgcn_mfma_f32_16x16x32_bf16(
                        avx[kco][rb], wfx[nb][kco], o[rb][nb], 0, 0, 0);

        // layer-2 tanh (o pre-scaled) + y-weighted accumulate
        float yj = ys[jj];
#pragma unroll
        for (int rb = 0; rb < 2; ++rb)
#pragma unroll
            for (int nb = 0; nb < 4; ++nb)
#pragma unroll
                for (int r = 0; r < 4; ++r)
                    acc[rb][nb][r] = __builtin_fmaf(yj, tanh_pre(o[rb][nb][r]),
                                                    acc[rb][nb][r]);
    }

    // epilogue: fold W3 over this wave's 64 n, reduce across l16, write partial
    float s[2][4];
#pragma unroll
    for (int rb = 0; rb < 2; ++rb)
#pragma unroll
        for (int r = 0; r < 4; ++r) {
            float v = 0.f;
#pragma unroll
            for (int nb = 0; nb < 4; ++nb)
                v = __builtin_fmaf(acc[rb][nb][r], w3v[nb], v);
            s[rb][r] = v;
        }
#pragma unroll
    for (int m = 1; m < 16; m <<= 1)
#pragma unroll
        for (int rb = 0; rb < 2; ++rb)
#pragma unroll
            for (int r = 0; r < 4; ++r)
                s[rb][r] += __shfl_xor(s[rb][r], m);

    if (l16 == 0) {
        float* dst = Sp + (blockIdx.y * 2 + p) * N_IN;
#pragma unroll
        for (int rb = 0; rb < 2; ++rb)
#pragma unroll
            for (int r = 0; r < 4; ++r)
                dst[ibW + rb * 16 + lg * 4 + r] = s[rb][r];
    }
}

// ---------------------------------------------------------------------------
// k_fin: out[i] = sum_{s<64} Sp[s][i] + b3*sumy.  grid 8 x 256.
// ---------------------------------------------------------------------------
__global__ void k_fin(const float* __restrict__ Sp, const float* __restrict__ b3,
                      const float* __restrict__ ws, float* __restrict__ out) {
    int i = blockIdx.x * 256 + threadIdx.x;
    float acc = b3[0] * ws[WS_SUMY_OFF >> 2];
#pragma unroll
    for (int s = 0; s < 2 * JC; ++s) acc += Sp[s * N_IN + i];
    out[i] = acc;
}

// ---------------------------------------------------------------------------
extern "C" void kernel_launch(void* const* d_in, const int* in_sizes, int n_in,
                              void* d_out, int out_size, void* d_ws, size_t ws_size,
                              hipStream_t stream) {
    const float* input = (const float*)d_in[0];
    const float* qx    = (const float*)d_in[1];
    const float* eq    = (const float*)d_in[2];
    const float* W1    = (const float*)d_in[3];
    const float* b1    = (const float*)d_in[4];
    const float* W2    = (const float*)d_in[5];
    const float* b2    = (const float*)d_in[6];
    const float* W3    = (const float*)d_in[7];
    const float* b3    = (const float*)d_in[8];
    float* out = (float*)d_out;
    float* ws  = (float*)d_ws;

    const float* A = ws + (WS_A_OFF >> 2);
    const float* B = ws + (WS_B_OFF >> 2);
    const float* Y = ws + (WS_Y_OFF >> 2);
    const unsigned short* W2T = (const unsigned short*)((char*)d_ws + WS_W2T_OFF);
    float* Sp = (float*)((char*)d_ws + WS_SP_OFF);

    k_pre<<<1345, 256, 0, stream>>>(input, qx, eq, W1, b1, W2, ws);
    k_main<<<dim3(64, JC), 128, 0, stream>>>(A, B, Y, W2T, b2, W3, Sp);
    k_fin<<<8, 256, 0, stream>>>(Sp, b3, ws, out);
}

// Round 5
// 91.292 us; speedup vs baseline: 2.5586x; 1.2144x over previous
//
#include <hip/hip_runtime.h>
#include <hip/hip_bf16.h>

// ---------------------------------------------------------------------------
// Modnet2: out[i] = sum_j y_j * ( tanh( tanh(A_i + B_j) @ W2 + b2 ) @ W3 + b3 )
//   A[i][h] = s*(input[i,0:2] @ W1[0:2,h])          (s = 2*log2(e) folded in)
//   B[j][h] = s*(quad_x[j,0:2] @ W1[2:4,h] + b1[h])
//   W2T/b2 pre-scaled by s, so tanh(x) = 1 - 2*rcp(1 + exp2(x_scaled)).
//
// R5: i-split decomposition. Each wave owns 16 i x ALL 128 n, so layer-1
// fragments are wave-private (computed exactly once chip-wide) and there are
// ZERO inner-loop barriers. W2 lives in LDS (XOR-swizzled vs 16-way slot
// aliasing on ds_read_b128). Block = 4 waves = 64 i x 16 j; grid 32x32.
// LDS 40.5KB -> 3 blocks/CU = 12 waves/CU, no exchange, no dbuf.
// ---------------------------------------------------------------------------

using short8 = __attribute__((ext_vector_type(8))) short;   // 8 bf16 = 4 VGPR
using f32x4  = __attribute__((ext_vector_type(4))) float;   // MFMA C/D frag

#define N_IN   2048
#define M_Q    512
#define H_DIM  128
#define JC     32
#define JCHUNK 16      // M_Q / JC

// ws byte offsets
#define WS_A_OFF     0x000000u   // 2048*128 f32 = 1 MiB   (pre-scaled)
#define WS_B_OFF     0x100000u   //  512*128 f32 = 256 KiB (pre-scaled)
#define WS_Y_OFF     0x140000u   //  512 f32
#define WS_SUMY_OFF  0x140800u   //  1 f32
#define WS_W2T_OFF   0x141000u   //  128*128 bf16 = 32 KiB (pre-scaled)
#define WS_SP_OFF    0x150000u   //  32 * 2048 f32 = 256 KiB (n-reduced partials)

#define PI_F   3.14159265358979323846f
#define TSCALE 2.885390081777927f   // 2*log2(e)

// x pre-scaled by TSCALE: tanh = 1 - 2/(1+e^{2x}) = 1 - 2*rcp(1+exp2(xs))
__device__ __forceinline__ float tanh_pre(float xs) {
    float t = __builtin_amdgcn_exp2f(xs);
    float r = __builtin_amdgcn_rcpf(1.0f + t);
    return __builtin_fmaf(-2.0f, r, 1.0f);
}

__device__ __forceinline__ unsigned short bf16b(float f) {
    __hip_bfloat16 h = __float2bfloat16(f);   // RNE
    unsigned short u;
    __builtin_memcpy(&u, &h, 2);
    return u;
}

// one MFMA A-fragment: 8 bf16 = tanh(a + b), inputs pre-scaled
__device__ __forceinline__ void conv8(const float4& a0, const float4& a1,
                                      const float4& b0, const float4& b1,
                                      short8& dst) {
    dst[0] = (short)bf16b(tanh_pre(a0.x + b0.x));
    dst[1] = (short)bf16b(tanh_pre(a0.y + b0.y));
    dst[2] = (short)bf16b(tanh_pre(a0.z + b0.z));
    dst[3] = (short)bf16b(tanh_pre(a0.w + b0.w));
    dst[4] = (short)bf16b(tanh_pre(a1.x + b1.x));
    dst[5] = (short)bf16b(tanh_pre(a1.y + b1.y));
    dst[6] = (short)bf16b(tanh_pre(a1.z + b1.z));
    dst[7] = (short)bf16b(tanh_pre(a1.w + b1.w));
}

// ---------------------------------------------------------------------------
// k_pre: A, B (scaled), y, sumy, W2T (scaled bf16).  grid 257 x 256.
// ---------------------------------------------------------------------------
__global__ void k_pre(const float* __restrict__ input, const float* __restrict__ qx,
                      const float* __restrict__ eq, const float* __restrict__ W1,
                      const float* __restrict__ b1, const float* __restrict__ W2,
                      float* __restrict__ ws) {
    int b = blockIdx.x, t = threadIdx.x;
    float* A = ws + (WS_A_OFF >> 2);
    float* B = ws + (WS_B_OFF >> 2);
    float* Y = ws + (WS_Y_OFF >> 2);
    unsigned short* W2T = (unsigned short*)((char*)ws + WS_W2T_OFF);

    if (b < 256) {
        int u = b * 256 + t;              // 0..65535
#pragma unroll
        for (int rep = 0; rep < 4; ++rep) {   // A: 262144 elems
            int idx = u + rep * 65536;
            int i = idx >> 7, h = idx & 127;
            A[idx] = TSCALE * (input[2 * i] * W1[h] + input[2 * i + 1] * W1[128 + h]);
        }
        {                                   // B: 65536 elems
            int j = u >> 7, h = u & 127;
            B[u] = TSCALE * (qx[2 * j] * W1[256 + h] + qx[2 * j + 1] * W1[384 + h] + b1[h]);
        }
        if (u < 16384) {                    // W2T[n][k] = bf16(s*W2[k][n])
            int n = u >> 7, k = u & 127;
            W2T[u] = bf16b(TSCALE * W2[k * 128 + n]);
        }
    } else {                                // y[j], sumy (single block)
        float e = eq[0];
        float s = 0.f;
#pragma unroll
        for (int rep = 0; rep < 2; ++rep) {
            int j = t + rep * 256;
            float yv = sinf(PI_F * e * qx[2 * j]) * sinf(PI_F * e * qx[2 * j + 1]);
            Y[j] = yv;
            s += yv;
        }
        __shared__ float red[4];
        for (int off = 32; off; off >>= 1) s += __shfl_down(s, off);
        if ((t & 63) == 0) red[t >> 6] = s;
        __syncthreads();
        if (t == 0) ws[WS_SUMY_OFF >> 2] = red[0] + red[1] + red[2] + red[3];
    }
}

// ---------------------------------------------------------------------------
// k_main. grid (32 i-blocks, 32 j-chunks) x 256 threads (4 waves).
// Wave w owns rows [blk*64 + w*16, +16), all 128 n. No inner barriers.
// mfma_f32_16x16x32_bf16 layout (verified R1-R4):
//   A: lane l -> row l&15, k=(l>>4)*8+e ; B: lane l -> col l&15, k=(l>>4)*8+e
//   D: lane l reg r -> row (l>>4)*4+r, col l&15
// W2s LDS swizzle: row n at byte n*256 + (colbyte ^ ((n&7)<<4)) so the 16
// rows of a b128 frag-read spread across 8 16B-slot positions (BW floor).
// ---------------------------------------------------------------------------
__global__ __launch_bounds__(256, 2)
void k_main(const float* __restrict__ A, const float* __restrict__ B,
            const float* __restrict__ Y, const unsigned short* __restrict__ W2T,
            const float* __restrict__ b2, const float* __restrict__ W3,
            float* __restrict__ Sp) {
    __shared__ unsigned short W2s[128 * 128];           // 32 KB, swizzled
    __shared__ float Bs[JCHUNK * 128];                  // 8 KB
    __shared__ float ys[JCHUNK];

    int t = threadIdx.x;
    int wave = t >> 6, lane = t & 63;
    int l16 = lane & 15, lg = lane >> 4;
    int i0 = blockIdx.x * 64 + wave * 16;
    int jbase = blockIdx.y * JCHUNK;

    // stage W2 (swizzled), 2048 x 16B chunks
    for (int c = t; c < 2048; c += 256) {
        int n = c >> 4, cb = c & 15;
        short8 v = *(const short8*)(W2T + c * 8);
        int dst = n * 128 + ((((cb * 16) ^ ((n & 7) << 4))) >> 1);   // in shorts
        *(short8*)&W2s[dst] = v;
    }
    // stage B chunk + y
    for (int o4 = t; o4 < (JCHUNK * 128) >> 2; o4 += 256)
        *(float4*)&Bs[o4 * 4] = *(const float4*)&B[jbase * 128 + o4 * 4];
    if (t < JCHUNK) ys[t] = Y[jbase + t];

    // A-addends: aa[kc][2] for this wave's 16 rows (row = l16)
    float4 aa[4][2];
#pragma unroll
    for (int kc = 0; kc < 4; ++kc) {
        const float* pa = &A[(i0 + l16) * 128 + kc * 32 + lg * 8];
        aa[kc][0] = *(const float4*)pa;
        aa[kc][1] = *(const float4*)(pa + 4);
    }

    float b2v[8];
#pragma unroll
    for (int nb = 0; nb < 8; ++nb) b2v[nb] = TSCALE * b2[nb * 16 + l16];

    // swizzled column byte-offsets for the wf reads (per kc)
    int colb[4];
#pragma unroll
    for (int kc = 0; kc < 4; ++kc)
        colb[kc] = (kc * 64 + lg * 16) ^ ((l16 & 7) << 4);
    const char* wbase = (const char*)W2s + l16 * 256;

    __syncthreads();

    f32x4 acc[8] = {};

#pragma unroll 1
    for (int jj = 0; jj < JCHUNK; ++jj) {
        f32x4 o[8];
#pragma unroll
        for (int nb = 0; nb < 8; ++nb) {
            o[nb][0] = b2v[nb]; o[nb][1] = b2v[nb];
            o[nb][2] = b2v[nb]; o[nb][3] = b2v[nb];
        }

#pragma unroll
        for (int kc = 0; kc < 4; ++kc) {
            const float* bp = &Bs[jj * 128 + kc * 32 + lg * 8];
            float4 bj0 = *(const float4*)bp;
            float4 bj1 = *(const float4*)(bp + 4);
            short8 av;
            conv8(aa[kc][0], aa[kc][1], bj0, bj1, av);
#pragma unroll
            for (int nb = 0; nb < 8; ++nb) {
                short8 wf = *(const short8*)(wbase + nb * 4096 + colb[kc]);
                o[nb] = __builtin_amdgcn_mfma_f32_16x16x32_bf16(av, wf, o[nb], 0, 0, 0);
            }
        }

        // layer-2 tanh (o pre-scaled) + y-weighted accumulate
        float yj = ys[jj];
#pragma unroll
        for (int nb = 0; nb < 8; ++nb)
#pragma unroll
            for (int r = 0; r < 4; ++r)
                acc[nb][r] = __builtin_fmaf(yj, tanh_pre(o[nb][r]), acc[nb][r]);
    }

    // epilogue: fold W3 over all 128 n, reduce across the 16 l16 lanes
    float w3v[8];
#pragma unroll
    for (int nb = 0; nb < 8; ++nb) w3v[nb] = W3[nb * 16 + l16];

    float s[4];
#pragma unroll
    for (int r = 0; r < 4; ++r) {
        float v = 0.f;
#pragma unroll
        for (int nb = 0; nb < 8; ++nb)
            v = __builtin_fmaf(acc[nb][r], w3v[nb], v);
        s[r] = v;
    }
#pragma unroll
    for (int m = 1; m < 16; m <<= 1)
#pragma unroll
        for (int r = 0; r < 4; ++r)
            s[r] += __shfl_xor(s[r], m);

    if (l16 == 0) {
        float* dst = Sp + blockIdx.y * N_IN;
#pragma unroll
        for (int r = 0; r < 4; ++r)
            dst[i0 + lg * 4 + r] = s[r];
    }
}

// ---------------------------------------------------------------------------
// k_fin: out[i] = sum_{jc<32} Sp[jc][i] + b3*sumy.  grid 8 x 256.
// ---------------------------------------------------------------------------
__global__ void k_fin(const float* __restrict__ Sp, const float* __restrict__ b3,
                      const float* __restrict__ ws, float* __restrict__ out) {
    int i = blockIdx.x * 256 + threadIdx.x;
    float acc = b3[0] * ws[WS_SUMY_OFF >> 2];
#pragma unroll
    for (int s = 0; s < JC; ++s) acc += Sp[s * N_IN + i];
    out[i] = acc;
}

// ---------------------------------------------------------------------------
extern "C" void kernel_launch(void* const* d_in, const int* in_sizes, int n_in,
                              void* d_out, int out_size, void* d_ws, size_t ws_size,
                              hipStream_t stream) {
    const float* input = (const float*)d_in[0];
    const float* qx    = (const float*)d_in[1];
    const float* eq    = (const float*)d_in[2];
    const float* W1    = (const float*)d_in[3];
    const float* b1    = (const float*)d_in[4];
    const float* W2    = (const float*)d_in[5];
    const float* b2    = (const float*)d_in[6];
    const float* W3    = (const float*)d_in[7];
    const float* b3    = (const float*)d_in[8];
    float* out = (float*)d_out;
    float* ws  = (float*)d_ws;

    const float* A = ws + (WS_A_OFF >> 2);
    const float* B = ws + (WS_B_OFF >> 2);
    const float* Y = ws + (WS_Y_OFF >> 2);
    const unsigned short* W2T = (const unsigned short*)((char*)d_ws + WS_W2T_OFF);
    float* Sp = (float*)((char*)d_ws + WS_SP_OFF);

    k_pre<<<257, 256, 0, stream>>>(input, qx, eq, W1, b1, W2, ws);
    k_main<<<dim3(32, JC), 256, 0, stream>>>(A, B, Y, W2T, b2, W3, Sp);
    k_fin<<<8, 256, 0, stream>>>(Sp, b3, ws, out);
}